// Round 4
// baseline (277.820 us; speedup 1.0000x reference)
//
#include <hip/hip_runtime.h>

// Problem constants
#define NNODES 64
#define HID 32
#define NFACT 3
#define NE 1024
#define NROWS (NE + NFACT)   // 1027
#define TPB 256
#define STR 36               // row stride (floats) for xpp and qp: float4 rows, 2-way bank alias only

typedef short bf16x8 __attribute__((ext_vector_type(8)));   // 8 bf16 (4 VGPRs)
typedef float f32x4  __attribute__((ext_vector_type(4)));   // MFMA accumulator

// fp32 -> bf16 round-to-nearest-even
__device__ __forceinline__ short f2bf(float f) {
    unsigned u = __builtin_bit_cast(unsigned, f);
    u += 0x7fffu + ((u >> 16) & 1u);
    return (short)(u >> 16);
}
__device__ __forceinline__ float4 fma4(float a, float4 w, float4 c) {
    c.x = fmaf(a, w.x, c.x); c.y = fmaf(a, w.y, c.y);
    c.z = fmaf(a, w.z, c.z); c.w = fmaf(a, w.w, c.w);
    return c;
}
__device__ __forceinline__ float4 add4(float4 a, float4 b) {
    return make_float4(a.x + b.x, a.y + b.y, a.z + b.z, a.w + b.w);
}

// Fused per-graph kernel (factored):
//   Q1[n]=b1+x[n]@W1[0:4]  Q2[n]=x[n]@W1[4:8]
//   h1(e)=relu(Q1[s]+Q2[d]+ea.x*W1[8]+ea.y*W1[9]);  msg=h1@W2+b2 (bf16 MFMA)
//   xpp[s]+=msg (LDS ds_add, MFMA C-layout)
//   P1[n]=bl+[x,xpp][n]@Wl[0:36]  P2[n]=[x,xpp][n]@Wl[36:72]
//   v(r)=bv+relu(P1[na]+P2[nb]+a*Wl[72]).Wv ; out[b]=sum_r v(r)
// All dynamically-indexed weights live in LDS (no SMEM lgkm-drain / uniformity gamble).
__global__ __launch_bounds__(TPB, 4) void critic_fused(
    const float* __restrict__ x,          // [B*64, 4]
    const float* __restrict__ edge_attr,  // [B*1024, 2]
    const float* __restrict__ action,     // [B, 1027]
    const int*   __restrict__ es,         // [1024]
    const int*   __restrict__ ed,         // [1024]
    const float* __restrict__ W1,         // [10, 32]
    const float* __restrict__ b1,         // [32]
    const float* __restrict__ W2,         // [32, 32]
    const float* __restrict__ b2,         // [32]
    const float* __restrict__ Wl,         // [73, 32]
    const float* __restrict__ bl,         // [32]
    const float* __restrict__ Wv,         // [32]
    const float* __restrict__ bv,         // [1]
    float* __restrict__ out)              // [B]
{
    const int b    = blockIdx.x;
    const int tid  = threadIdx.x;
    const int lane = tid & 63;
    const int wv   = tid >> 6;

    __shared__ float4 xs4[NNODES];            // node input feats
    __shared__ float  xpp[NNODES * STR];      // conv accumulator (atomic target)
    __shared__ float  qp0[NNODES * STR];      // Q1 then P1
    __shared__ float  qp1[NNODES * STR];      // Q2 then P2
    __shared__ float  W1s[10 * HID];          // 1.25 KB
    __shared__ float  Wls[73 * HID];          // 9.1 KB
    __shared__ float  b1s[HID], bls[HID];
    __shared__ float  wred[TPB / 64];

    // ---- Stage A: stage x + weights, zero xpp ----
    if (tid < NNODES) xs4[tid] = ((const float4*)x)[b * NNODES + tid];
    {
        float4*       W1s4 = (float4*)W1s;
        const float4* W1g  = (const float4*)W1;
        if (tid < 80) W1s4[tid] = W1g[tid];                       // 10*32/4
        float4*       Wls4 = (float4*)Wls;
        const float4* Wlg  = (const float4*)Wl;
        for (int i = tid; i < 73 * HID / 4; i += TPB) Wls4[i] = Wlg[i];
        if (tid < HID) { b1s[tid] = b1[tid]; bls[tid] = bl[tid]; }
    }
    for (int i = tid; i < NNODES * STR; i += TPB) xpp[i] = 0.0f;
    __syncthreads();

    const int n  = tid & 63;       // node owned in Q/P stages
    const int k0 = (tid >> 6) * 8; // 8-wide output slice

    // ---- Stage Q: per-node first-layer partials (weights from LDS) ----
    {
        const float4 xv = xs4[n];
        const float xa[4] = {xv.x, xv.y, xv.z, xv.w};
        const float4* b1v = (const float4*)&b1s[k0];
        float4 q1a = b1v[0], q1b = b1v[1];
        float4 q2a = make_float4(0.f, 0.f, 0.f, 0.f), q2b = q2a;
#pragma unroll
        for (int i = 0; i < 4; i++) {
            const float4* wa = (const float4*)&W1s[i * HID + k0];
            const float4* wb = (const float4*)&W1s[(4 + i) * HID + k0];
            q1a = fma4(xa[i], wa[0], q1a); q1b = fma4(xa[i], wa[1], q1b);
            q2a = fma4(xa[i], wb[0], q2a); q2b = fma4(xa[i], wb[1], q2b);
        }
        float4* q1w = (float4*)&qp0[n * STR + k0];
        float4* q2w = (float4*)&qp1[n * STR + k0];
        q1w[0] = q1a; q1w[1] = q1b;
        q2w[0] = q2a; q2w[1] = q2b;
    }
    __syncthreads();

    // ---- Stage B: edge messages via MFMA + LDS scatter-add (2 tiles/iter) ----
    {
        const float2* ea2 = (const float2*)edge_attr + (size_t)b * NE;
        const int quad = lane >> 4;
        const int m16  = lane & 15;
        const int kh   = quad * 8;

        const float4* w8p = (const float4*)&W1s[8 * HID + kh];
        const float4* w9p = (const float4*)&W1s[9 * HID + kh];
        const float4 w8a = w8p[0], w8b = w8p[1];
        const float4 w9a = w9p[0], w9b = w9p[1];
        const float b2c0 = b2[m16];
        const float b2c1 = b2[16 + m16];

        bf16x8 bf0, bf1;        // W2 B-fragments (column halves)
#pragma unroll
        for (int j = 0; j < 8; j++) {
            bf0[j] = f2bf(W2[(kh + j) * HID + m16]);
            bf1[j] = f2bf(W2[(kh + j) * HID + 16 + m16]);
        }

#pragma unroll 2
        for (int jt = 0; jt < 16; jt += 2) {
            const int t0 = wv + jt * 4;
            const int t1 = t0 + 4;
            // hoisted index/attr loads (independent chains)
            const int eA0 = t0 * 16 + m16, eA1 = t1 * 16 + m16;
            const int s0 = es[eA0], d0 = ed[eA0];
            const int s1 = es[eA1], d1 = ed[eA1];
            const float2 eaA = ea2[eA0], eaB = ea2[eA1];
            int sc0[4], sc1[4];
#pragma unroll
            for (int r = 0; r < 4; r++) {
                sc0[r] = es[t0 * 16 + quad * 4 + r];
                sc1[r] = es[t1 * 16 + quad * 4 + r];
            }
            // LDS gathers for both tiles
            const float4* q1p0 = (const float4*)&qp0[s0 * STR + kh];
            const float4* q2p0 = (const float4*)&qp1[d0 * STR + kh];
            const float4* q1p1 = (const float4*)&qp0[s1 * STR + kh];
            const float4* q2p1 = (const float4*)&qp1[d1 * STR + kh];
            const float4 a00 = q1p0[0], a01 = q1p0[1], b00 = q2p0[0], b01 = q2p0[1];
            const float4 a10 = q1p1[0], a11 = q1p1[1], b10 = q2p1[0], b11 = q2p1[1];

            bf16x8 af0, af1;
            {
                const float4 h0 = add4(add4(a00, b00), add4(fma4(eaA.x, w8a, make_float4(0,0,0,0)), fma4(eaA.y, w9a, make_float4(0,0,0,0))));
                const float4 h1 = add4(add4(a01, b01), add4(fma4(eaA.x, w8b, make_float4(0,0,0,0)), fma4(eaA.y, w9b, make_float4(0,0,0,0))));
                af0[0] = f2bf(fmaxf(h0.x, 0.f)); af0[1] = f2bf(fmaxf(h0.y, 0.f));
                af0[2] = f2bf(fmaxf(h0.z, 0.f)); af0[3] = f2bf(fmaxf(h0.w, 0.f));
                af0[4] = f2bf(fmaxf(h1.x, 0.f)); af0[5] = f2bf(fmaxf(h1.y, 0.f));
                af0[6] = f2bf(fmaxf(h1.z, 0.f)); af0[7] = f2bf(fmaxf(h1.w, 0.f));
            }
            {
                const float4 h0 = add4(add4(a10, b10), add4(fma4(eaB.x, w8a, make_float4(0,0,0,0)), fma4(eaB.y, w9a, make_float4(0,0,0,0))));
                const float4 h1 = add4(add4(a11, b11), add4(fma4(eaB.x, w8b, make_float4(0,0,0,0)), fma4(eaB.y, w9b, make_float4(0,0,0,0))));
                af1[0] = f2bf(fmaxf(h0.x, 0.f)); af1[1] = f2bf(fmaxf(h0.y, 0.f));
                af1[2] = f2bf(fmaxf(h0.z, 0.f)); af1[3] = f2bf(fmaxf(h0.w, 0.f));
                af1[4] = f2bf(fmaxf(h1.x, 0.f)); af1[5] = f2bf(fmaxf(h1.y, 0.f));
                af1[6] = f2bf(fmaxf(h1.z, 0.f)); af1[7] = f2bf(fmaxf(h1.w, 0.f));
            }

            f32x4 c00 = {0.f,0.f,0.f,0.f}, c01 = c00, c10 = c00, c11 = c00;
            c00 = __builtin_amdgcn_mfma_f32_16x16x32_bf16(af0, bf0, c00, 0, 0, 0);
            c01 = __builtin_amdgcn_mfma_f32_16x16x32_bf16(af0, bf1, c01, 0, 0, 0);
            c10 = __builtin_amdgcn_mfma_f32_16x16x32_bf16(af1, bf0, c10, 0, 0, 0);
            c11 = __builtin_amdgcn_mfma_f32_16x16x32_bf16(af1, bf1, c11, 0, 0, 0);

            // C layout: row=quad*4+r (edge), col=m16 (k) -> scatter to xpp
#pragma unroll
            for (int r = 0; r < 4; r++) {
                float* xr0 = &xpp[sc0[r] * STR];
                atomicAdd(&xr0[m16],      c00[r] + b2c0);
                atomicAdd(&xr0[16 + m16], c01[r] + b2c1);
            }
#pragma unroll
            for (int r = 0; r < 4; r++) {
                float* xr1 = &xpp[sc1[r] * STR];
                atomicAdd(&xr1[m16],      c10[r] + b2c0);
                atomicAdd(&xr1[16 + m16], c11[r] + b2c1);
            }
        }
    }
    __syncthreads();

    // ---- Stage P: per-node head projections (weights from LDS, xpp via float4) ----
    {
        const float4 xv = xs4[n];
        const float xa[4] = {xv.x, xv.y, xv.z, xv.w};
        float xp[HID];
        const float4* xrv = (const float4*)&xpp[n * STR];
#pragma unroll
        for (int q = 0; q < 8; q++) {
            const float4 v = xrv[q];
            xp[4*q] = v.x; xp[4*q+1] = v.y; xp[4*q+2] = v.z; xp[4*q+3] = v.w;
        }
        const float4* blv = (const float4*)&bls[k0];
        float4 p1a = blv[0], p1b = blv[1];
        float4 p2a = make_float4(0.f,0.f,0.f,0.f), p2b = p2a;
#pragma unroll
        for (int i = 0; i < 4; i++) {
            const float4* wa = (const float4*)&Wls[i * HID + k0];
            const float4* wb = (const float4*)&Wls[(36 + i) * HID + k0];
            p1a = fma4(xa[i], wa[0], p1a); p1b = fma4(xa[i], wa[1], p1b);
            p2a = fma4(xa[i], wb[0], p2a); p2b = fma4(xa[i], wb[1], p2b);
        }
#pragma unroll
        for (int j = 0; j < HID; j++) {
            const float xj = xp[j];
            const float4* wa = (const float4*)&Wls[(4 + j) * HID + k0];
            const float4* wb = (const float4*)&Wls[(40 + j) * HID + k0];
            p1a = fma4(xj, wa[0], p1a); p1b = fma4(xj, wa[1], p1b);
            p2a = fma4(xj, wb[0], p2a); p2b = fma4(xj, wb[1], p2b);
        }
        float4* p1w = (float4*)&qp0[n * STR + k0];
        float4* p2w = (float4*)&qp1[n * STR + k0];
        p1w[0] = p1a; p1w[1] = p1b;
        p2w[0] = p2a; p2w[1] = p2b;
    }
    __syncthreads();

    // ---- Stage C: per-row combine + value head (2 rows/iter) ----
    float vsum = 0.0f;
    {
        const float* actb = action + (size_t)b * NROWS;
        const float bvv = bv[0];
        const float* Wl72 = Wl + 72 * HID;   // literal-indexed -> hoisted s_loads

#pragma unroll
        for (int rr = 0; rr < 4; rr += 2) {
            const int rA = tid + rr * TPB;
            const int rB = rA + TPB;
            const int naA = es[rA], nbA = ed[rA];
            const int naB = es[rB], nbB = ed[rB];
            const float aA = actb[rA], aB = actb[rB];
            const float4* p1A = (const float4*)&qp0[naA * STR];
            const float4* p2A = (const float4*)&qp1[nbA * STR];
            const float4* p1B = (const float4*)&qp0[naB * STR];
            const float4* p2B = (const float4*)&qp1[nbB * STR];
            float vA = bvv, vB = bvv;
#pragma unroll
            for (int q = 0; q < 8; q++) {
                const float4 paA = p1A[q], pbA = p2A[q];
                const float4 paB = p1B[q], pbB = p2B[q];
                const int k = q * 4;
                vA += fmaxf(paA.x + pbA.x + aA * Wl72[k+0], 0.f) * Wv[k+0];
                vA += fmaxf(paA.y + pbA.y + aA * Wl72[k+1], 0.f) * Wv[k+1];
                vA += fmaxf(paA.z + pbA.z + aA * Wl72[k+2], 0.f) * Wv[k+2];
                vA += fmaxf(paA.w + pbA.w + aA * Wl72[k+3], 0.f) * Wv[k+3];
                vB += fmaxf(paB.x + pbB.x + aB * Wl72[k+0], 0.f) * Wv[k+0];
                vB += fmaxf(paB.y + pbB.y + aB * Wl72[k+1], 0.f) * Wv[k+1];
                vB += fmaxf(paB.z + pbB.z + aB * Wl72[k+2], 0.f) * Wv[k+2];
                vB += fmaxf(paB.w + pbB.w + aB * Wl72[k+3], 0.f) * Wv[k+3];
            }
            vsum += vA + vB;
        }
        // factory rows 1024..1026 (na == nb)
        if (tid < NFACT) {
            const int r = NE + tid;
            const int na = NNODES - NFACT + tid;
            const float a = actb[r];
            const float4* p1v = (const float4*)&qp0[na * STR];
            const float4* p2v = (const float4*)&qp1[na * STR];
            float v = bvv;
#pragma unroll
            for (int q = 0; q < 8; q++) {
                const float4 pa = p1v[q], pb = p2v[q];
                const int k = q * 4;
                v += fmaxf(pa.x + pb.x + a * Wl72[k+0], 0.f) * Wv[k+0];
                v += fmaxf(pa.y + pb.y + a * Wl72[k+1], 0.f) * Wv[k+1];
                v += fmaxf(pa.z + pb.z + a * Wl72[k+2], 0.f) * Wv[k+2];
                v += fmaxf(pa.w + pb.w + a * Wl72[k+3], 0.f) * Wv[k+3];
            }
            vsum += v;
        }
    }

    // ---- block reduction ----
#pragma unroll
    for (int off = 32; off > 0; off >>= 1)
        vsum += __shfl_down(vsum, off, 64);
    if ((tid & 63) == 0) wred[tid >> 6] = vsum;
    __syncthreads();
    if (tid == 0) {
        float t = 0.0f;
#pragma unroll
        for (int w = 0; w < TPB / 64; w++) t += wred[w];
        out[b] = t;
    }
}

extern "C" void kernel_launch(void* const* d_in, const int* in_sizes, int n_in,
                              void* d_out, int out_size, void* d_ws, size_t ws_size,
                              hipStream_t stream) {
    const float* x         = (const float*)d_in[0];
    // d_in[1] = edge_index (redundant: es/ed + per-graph offset)
    const float* edge_attr = (const float*)d_in[2];
    const float* action    = (const float*)d_in[3];
    const int*   es        = (const int*)d_in[4];
    const int*   ed        = (const int*)d_in[5];
    const float* W1        = (const float*)d_in[6];
    const float* b1        = (const float*)d_in[7];
    const float* W2        = (const float*)d_in[8];
    const float* b2        = (const float*)d_in[9];
    const float* Wl        = (const float*)d_in[10];
    const float* bl        = (const float*)d_in[11];
    const float* Wv        = (const float*)d_in[12];
    const float* bv        = (const float*)d_in[13];
    float* out = (float*)d_out;

    critic_fused<<<dim3(out_size), dim3(TPB), 0, stream>>>(
        x, edge_attr, action, es, ed, W1, b1, W2, b2, Wl, bl, Wv, bv, out);
}

// Round 5
// 272.806 us; speedup vs baseline: 1.0184x; 1.0184x over previous
//
#include <hip/hip_runtime.h>

// Problem constants
#define NNODES 64
#define HID 32
#define NFACT 3
#define NE 1024
#define NROWS (NE + NFACT)   // 1027
#define TPB 256
#define STR 36               // row stride (floats) for xpp/qp: float4 rows, 2-way bank alias only

typedef short bf16x8 __attribute__((ext_vector_type(8)));
typedef float f32x4  __attribute__((ext_vector_type(4)));

__device__ __forceinline__ short f2bf(float f) {
    unsigned u = __builtin_bit_cast(unsigned, f);
    u += 0x7fffu + ((u >> 16) & 1u);
    return (short)(u >> 16);
}
__device__ __forceinline__ float4 fma4(float a, float4 w, float4 c) {
    c.x = fmaf(a, w.x, c.x); c.y = fmaf(a, w.y, c.y);
    c.z = fmaf(a, w.z, c.z); c.w = fmaf(a, w.w, c.w);
    return c;
}

// Same factored algorithm as R4; loops ROLLED to shrink I-footprint (~4KB vs ~30KB).
// Theory: R1-R4's ~460k-cycle block latency with all pipes <10% busy is I$ streaming
// of the fully-unrolled megakernel; all waves walk the code in barrier lockstep.
__global__ __launch_bounds__(TPB, 4) void critic_fused(
    const float* __restrict__ x,
    const float* __restrict__ edge_attr,
    const float* __restrict__ action,
    const int*   __restrict__ es,
    const int*   __restrict__ ed,
    const float* __restrict__ W1,
    const float* __restrict__ b1,
    const float* __restrict__ W2,
    const float* __restrict__ b2,
    const float* __restrict__ Wl,
    const float* __restrict__ bl,
    const float* __restrict__ Wv,
    const float* __restrict__ bv,
    float* __restrict__ out)
{
    const int b    = blockIdx.x;
    const int tid  = threadIdx.x;
    const int lane = tid & 63;
    const int wv   = tid >> 6;

    __shared__ float4 xs4[NNODES];
    __shared__ float  xpp[NNODES * STR];
    __shared__ float  qp0[NNODES * STR];      // Q1 then P1
    __shared__ float  qp1[NNODES * STR];      // Q2 then P2
    __shared__ float  W1s[10 * HID];
    __shared__ float  Wls[73 * HID];
    __shared__ float  b1s[HID], bls[HID];
    __shared__ float  wred[TPB / 64];

    // ---- Stage A: stage x + weights, zero xpp (rolled) ----
    if (tid < NNODES) xs4[tid] = ((const float4*)x)[b * NNODES + tid];
    {
        float4*       W1s4 = (float4*)W1s;
        const float4* W1g  = (const float4*)W1;
        if (tid < 80) W1s4[tid] = W1g[tid];
        float4*       Wls4 = (float4*)Wls;
        const float4* Wlg  = (const float4*)Wl;
#pragma unroll 1
        for (int i = tid; i < 73 * HID / 4; i += TPB) Wls4[i] = Wlg[i];
        if (tid < HID) { b1s[tid] = b1[tid]; bls[tid] = bl[tid]; }
    }
#pragma unroll 1
    for (int i = tid; i < NNODES * STR; i += TPB) xpp[i] = 0.0f;
    __syncthreads();

    const int n  = tid & 63;
    const int k0 = (tid >> 6) * 8;

    // ---- Stage Q: per-node first-layer partials ----
    {
        const float4 xv = xs4[n];
        const float4* b1v = (const float4*)&b1s[k0];
        float4 q1a = b1v[0], q1b = b1v[1];
        float4 q2a = make_float4(0.f, 0.f, 0.f, 0.f), q2b = q2a;
#pragma unroll 1
        for (int i = 0; i < 4; i++) {
            const float xi = (i == 0) ? xv.x : (i == 1) ? xv.y : (i == 2) ? xv.z : xv.w;
            const float4* wa = (const float4*)&W1s[i * HID + k0];
            const float4* wb = (const float4*)&W1s[(4 + i) * HID + k0];
            q1a = fma4(xi, wa[0], q1a); q1b = fma4(xi, wa[1], q1b);
            q2a = fma4(xi, wb[0], q2a); q2b = fma4(xi, wb[1], q2b);
        }
        float4* q1w = (float4*)&qp0[n * STR + k0];
        float4* q2w = (float4*)&qp1[n * STR + k0];
        q1w[0] = q1a; q1w[1] = q1b;
        q2w[0] = q2a; q2w[1] = q2b;
    }
    __syncthreads();

    // ---- Stage B: edge messages via MFMA + LDS scatter-add (rolled, 1 tile/iter) ----
    {
        const float2* ea2 = (const float2*)edge_attr + (size_t)b * NE;
        const int quad = lane >> 4;
        const int m16  = lane & 15;
        const int kh   = quad * 8;

        const float4* w8p = (const float4*)&W1s[8 * HID + kh];
        const float4* w9p = (const float4*)&W1s[9 * HID + kh];
        const float4 w8a = w8p[0], w8b = w8p[1];
        const float4 w9a = w9p[0], w9b = w9p[1];
        const float b2c0 = b2[m16];
        const float b2c1 = b2[16 + m16];

        bf16x8 bf0, bf1;
#pragma unroll
        for (int j = 0; j < 8; j++) {
            bf0[j] = f2bf(W2[(kh + j) * HID + m16]);
            bf1[j] = f2bf(W2[(kh + j) * HID + 16 + m16]);
        }

#pragma unroll 1
        for (int t = wv; t < NE / 16; t += TPB / 64) {
            const int eA = t * 16 + m16;
            const int s0 = es[eA], d0 = ed[eA];
            const float2 ea = ea2[eA];
            const float4* q1p = (const float4*)&qp0[s0 * STR + kh];
            const float4* q2p = (const float4*)&qp1[d0 * STR + kh];
            const float4 a0 = q1p[0], a1 = q1p[1];
            const float4 g0 = q2p[0], g1 = q2p[1];

            bf16x8 af;
            af[0] = f2bf(fmaxf(a0.x + g0.x + ea.x * w8a.x + ea.y * w9a.x, 0.f));
            af[1] = f2bf(fmaxf(a0.y + g0.y + ea.x * w8a.y + ea.y * w9a.y, 0.f));
            af[2] = f2bf(fmaxf(a0.z + g0.z + ea.x * w8a.z + ea.y * w9a.z, 0.f));
            af[3] = f2bf(fmaxf(a0.w + g0.w + ea.x * w8a.w + ea.y * w9a.w, 0.f));
            af[4] = f2bf(fmaxf(a1.x + g1.x + ea.x * w8b.x + ea.y * w9b.x, 0.f));
            af[5] = f2bf(fmaxf(a1.y + g1.y + ea.x * w8b.y + ea.y * w9b.y, 0.f));
            af[6] = f2bf(fmaxf(a1.z + g1.z + ea.x * w8b.z + ea.y * w9b.z, 0.f));
            af[7] = f2bf(fmaxf(a1.w + g1.w + ea.x * w8b.w + ea.y * w9b.w, 0.f));

            f32x4 c0 = {0.f, 0.f, 0.f, 0.f};
            f32x4 c1 = {0.f, 0.f, 0.f, 0.f};
            c0 = __builtin_amdgcn_mfma_f32_16x16x32_bf16(af, bf0, c0, 0, 0, 0);
            c1 = __builtin_amdgcn_mfma_f32_16x16x32_bf16(af, bf1, c1, 0, 0, 0);

            const int rowbase = t * 16 + quad * 4;
            // unrolled r (dynamic c0[r] subscript must stay static)
            {
                float* xr = &xpp[es[rowbase + 0] * STR];
                atomicAdd(&xr[m16], c0[0] + b2c0);
                atomicAdd(&xr[16 + m16], c1[0] + b2c1);
            }
            {
                float* xr = &xpp[es[rowbase + 1] * STR];
                atomicAdd(&xr[m16], c0[1] + b2c0);
                atomicAdd(&xr[16 + m16], c1[1] + b2c1);
            }
            {
                float* xr = &xpp[es[rowbase + 2] * STR];
                atomicAdd(&xr[m16], c0[2] + b2c0);
                atomicAdd(&xr[16 + m16], c1[2] + b2c1);
            }
            {
                float* xr = &xpp[es[rowbase + 3] * STR];
                atomicAdd(&xr[m16], c0[3] + b2c0);
                atomicAdd(&xr[16 + m16], c1[3] + b2c1);
            }
        }
    }
    __syncthreads();

    // ---- Stage P: per-node head projections (rolled j-groups of 4) ----
    {
        const float4 xv = xs4[n];
        const float4* blv = (const float4*)&bls[k0];
        float4 p1a = blv[0], p1b = blv[1];
        float4 p2a = make_float4(0.f, 0.f, 0.f, 0.f), p2b = p2a;
#pragma unroll 1
        for (int i = 0; i < 4; i++) {
            const float xi = (i == 0) ? xv.x : (i == 1) ? xv.y : (i == 2) ? xv.z : xv.w;
            const float4* wa = (const float4*)&Wls[i * HID + k0];
            const float4* wb = (const float4*)&Wls[(36 + i) * HID + k0];
            p1a = fma4(xi, wa[0], p1a); p1b = fma4(xi, wa[1], p1b);
            p2a = fma4(xi, wb[0], p2a); p2b = fma4(xi, wb[1], p2b);
        }
        const float4* xrv = (const float4*)&xpp[n * STR];
#pragma unroll 1
        for (int q = 0; q < 8; q++) {
            const float4 xq = xrv[q];
            const int j = q * 4;
#pragma unroll
            for (int u = 0; u < 4; u++) {
                const float xj = (u == 0) ? xq.x : (u == 1) ? xq.y : (u == 2) ? xq.z : xq.w;
                const float4* wa = (const float4*)&Wls[(4 + j + u) * HID + k0];
                const float4* wb = (const float4*)&Wls[(40 + j + u) * HID + k0];
                p1a = fma4(xj, wa[0], p1a); p1b = fma4(xj, wa[1], p1b);
                p2a = fma4(xj, wb[0], p2a); p2b = fma4(xj, wb[1], p2b);
            }
        }
        float4* p1w = (float4*)&qp0[n * STR + k0];
        float4* p2w = (float4*)&qp1[n * STR + k0];
        p1w[0] = p1a; p1w[1] = p1b;
        p2w[0] = p2a; p2w[1] = p2b;
    }
    __syncthreads();

    // ---- Stage C: per-row combine + value head (rolled grid-stride) ----
    float vsum = 0.0f;
    {
        const float* actb = action + (size_t)b * NROWS;
        const float bvv = bv[0];
        const float* Wl72 = Wl + 72 * HID;   // loop-invariant s_loads, hoisted
#pragma unroll 1
        for (int r = tid; r < NROWS; r += TPB) {
            int na, nb;
            if (r < NE) { na = es[r]; nb = ed[r]; }
            else        { na = NNODES - NFACT + (r - NE); nb = na; }
            const float a = actb[r];
            const float4* p1v = (const float4*)&qp0[na * STR];
            const float4* p2v = (const float4*)&qp1[nb * STR];
            float v = bvv;
#pragma unroll 1
            for (int q = 0; q < 8; q += 2) {
                const float4 pa0 = p1v[q],     pb0 = p2v[q];
                const float4 pa1 = p1v[q + 1], pb1 = p2v[q + 1];
                const int k = q * 4;
                v += fmaxf(pa0.x + pb0.x + a * Wl72[k+0], 0.f) * Wv[k+0];
                v += fmaxf(pa0.y + pb0.y + a * Wl72[k+1], 0.f) * Wv[k+1];
                v += fmaxf(pa0.z + pb0.z + a * Wl72[k+2], 0.f) * Wv[k+2];
                v += fmaxf(pa0.w + pb0.w + a * Wl72[k+3], 0.f) * Wv[k+3];
                v += fmaxf(pa1.x + pb1.x + a * Wl72[k+4], 0.f) * Wv[k+4];
                v += fmaxf(pa1.y + pb1.y + a * Wl72[k+5], 0.f) * Wv[k+5];
                v += fmaxf(pa1.z + pb1.z + a * Wl72[k+6], 0.f) * Wv[k+6];
                v += fmaxf(pa1.w + pb1.w + a * Wl72[k+7], 0.f) * Wv[k+7];
            }
            vsum += v;
        }
    }

    // ---- block reduction ----
#pragma unroll
    for (int off = 32; off > 0; off >>= 1)
        vsum += __shfl_down(vsum, off, 64);
    if ((tid & 63) == 0) wred[tid >> 6] = vsum;
    __syncthreads();
    if (tid == 0) {
        float t = 0.0f;
#pragma unroll
        for (int w = 0; w < TPB / 64; w++) t += wred[w];
        out[b] = t;
    }
}

extern "C" void kernel_launch(void* const* d_in, const int* in_sizes, int n_in,
                              void* d_out, int out_size, void* d_ws, size_t ws_size,
                              hipStream_t stream) {
    const float* x         = (const float*)d_in[0];
    const float* edge_attr = (const float*)d_in[2];
    const float* action    = (const float*)d_in[3];
    const int*   es        = (const int*)d_in[4];
    const int*   ed        = (const int*)d_in[5];
    const float* W1        = (const float*)d_in[6];
    const float* b1        = (const float*)d_in[7];
    const float* W2        = (const float*)d_in[8];
    const float* b2        = (const float*)d_in[9];
    const float* Wl        = (const float*)d_in[10];
    const float* bl        = (const float*)d_in[11];
    const float* Wv        = (const float*)d_in[12];
    const float* bv        = (const float*)d_in[13];
    float* out = (float*)d_out;

    critic_fused<<<dim3(out_size), dim3(TPB), 0, stream>>>(
        x, edge_attr, action, es, ed, W1, b1, W2, b2, Wl, bl, Wv, bv, out);
}

// Round 6
// 149.764 us; speedup vs baseline: 1.8550x; 1.8216x over previous
//
#include <hip/hip_runtime.h>

// Problem constants
#define NNODES 64
#define HID 32
#define NFACT 3
#define NE 1024
#define NROWS (NE + NFACT)   // 1027
#define TPB 256
#define STR 36               // row stride (floats) for xpp/qp

// d_ws int layout: [0]=ntiles  [64..127]=deg[n]  [128..251]=tile_node[t]  [256..]=pe[t*16+i]
#define WS_DEG  64
#define WS_TN   128
#define WS_PE   256

typedef short bf16x8 __attribute__((ext_vector_type(8)));
typedef float f32x4  __attribute__((ext_vector_type(4)));

__device__ __forceinline__ short f2bf(float f) {
    unsigned u = __builtin_bit_cast(unsigned, f);
    u += 0x7fffu + ((u >> 16) & 1u);
    return (short)(u >> 16);
}
__device__ __forceinline__ float4 fma4(float a, float4 w, float4 c) {
    c.x = fmaf(a, w.x, c.x); c.y = fmaf(a, w.y, c.y);
    c.z = fmaf(a, w.z, c.z); c.w = fmaf(a, w.w, c.w);
    return c;
}

// ---- Kernel 0: build CSR of edges grouped by src, padded to 16-edge tiles ----
// Sum ceil(deg/16) <= (1024 + 64*15)/16 = 124 tiles. One block; runs every call.
__global__ __launch_bounds__(TPB) void build_csr(const int* __restrict__ es,
                                                 int* __restrict__ ws) {
    __shared__ int sdeg[NNODES], soff[NNODES], scnt[NNODES], snt;
    const int tid = threadIdx.x;
    if (tid < NNODES) { sdeg[tid] = 0; scnt[tid] = 0; }
    __syncthreads();
#pragma unroll 1
    for (int e = tid; e < NE; e += TPB) atomicAdd(&sdeg[es[e]], 1);
    __syncthreads();
    if (tid == 0) {
        int run = 0;
#pragma unroll 1
        for (int n = 0; n < NNODES; n++) { soff[n] = run; run += (sdeg[n] + 15) >> 4; }
        snt = run;
        ws[0] = run;
    }
    __syncthreads();
    const int ntiles = snt;
    if (tid < NNODES) {
        ws[WS_DEG + tid] = sdeg[tid];
        const int base = soff[tid], cnt = (sdeg[tid] + 15) >> 4;
#pragma unroll 1
        for (int j = 0; j < cnt; j++) ws[WS_TN + base + j] = tid;
    }
#pragma unroll 1
    for (int i = tid; i < ntiles * 16; i += TPB) ws[WS_PE + i] = -1;
    __syncthreads();
#pragma unroll 1
    for (int e = tid; e < NE; e += TPB) {
        const int n = es[e];
        const int idx = atomicAdd(&scnt[n], 1);
        ws[WS_PE + soff[n] * 16 + idx] = e;
    }
}

// ---- Kernel 1: fused per-graph critic ----
// Q1[n]=b1+x[n]@W1[0:4]  Q2[n]=x[n]@W1[4:8]
// per CSR tile (one dst node, <=16 edges): h1=relu(Q1[node]+Q2[d]+ea@W1[8:10]);
//   tile_msg_sum = colsum(h1 @ W2) via MFMA + in-register row reduction ->
//   single 32-lane contiguous ds_add into xpp[node]  (NO divergent LDS atomics)
// xpp_eff[n] = xpp[n] + deg[n]*b2   (b2-per-edge folded exactly)
// P1[n]=bl+[x,xpp_eff][n]@Wl[0:36]  P2[n]=[x,xpp_eff][n]@Wl[36:72]
// v(r)=bv+relu(P1[na]+P2[nb]+a*Wl[72]).Wv ; out[b]=sum_r v(r)
__global__ __launch_bounds__(TPB, 4) void critic_fused(
    const float* __restrict__ x,
    const float* __restrict__ edge_attr,
    const float* __restrict__ action,
    const int*   __restrict__ es,
    const int*   __restrict__ ed,
    const float* __restrict__ W1,
    const float* __restrict__ b1,
    const float* __restrict__ W2,
    const float* __restrict__ b2,
    const float* __restrict__ Wl,
    const float* __restrict__ bl,
    const float* __restrict__ Wv,
    const float* __restrict__ bv,
    const int*   __restrict__ csr,
    float* __restrict__ out)
{
    const int b    = blockIdx.x;
    const int tid  = threadIdx.x;
    const int lane = tid & 63;
    const int wv   = tid >> 6;

    __shared__ float4 xs4[NNODES];
    __shared__ float  xpp[NNODES * STR];
    __shared__ float  qp0[NNODES * STR];      // Q1 then P1
    __shared__ float  qp1[NNODES * STR];      // Q2 then P2
    __shared__ float  W1s[10 * HID];
    __shared__ float  Wls[73 * HID];
    __shared__ float  b1s[HID], bls[HID], b2s[HID];
    __shared__ float  wred[TPB / 64];

    // ---- Stage A: stage x + weights, zero xpp ----
    if (tid < NNODES) xs4[tid] = ((const float4*)x)[b * NNODES + tid];
    {
        float4*       W1s4 = (float4*)W1s;
        const float4* W1g  = (const float4*)W1;
        if (tid < 80) W1s4[tid] = W1g[tid];
        float4*       Wls4 = (float4*)Wls;
        const float4* Wlg  = (const float4*)Wl;
#pragma unroll 1
        for (int i = tid; i < 73 * HID / 4; i += TPB) Wls4[i] = Wlg[i];
        if (tid < HID) { b1s[tid] = b1[tid]; bls[tid] = bl[tid]; b2s[tid] = b2[tid]; }
    }
#pragma unroll 1
    for (int i = tid; i < NNODES * STR; i += TPB) xpp[i] = 0.0f;
    __syncthreads();

    const int n  = tid & 63;
    const int k0 = (tid >> 6) * 8;

    // ---- Stage Q: per-node first-layer partials ----
    {
        const float4 xv = xs4[n];
        const float4* b1v = (const float4*)&b1s[k0];
        float4 q1a = b1v[0], q1b = b1v[1];
        float4 q2a = make_float4(0.f, 0.f, 0.f, 0.f), q2b = q2a;
#pragma unroll 1
        for (int i = 0; i < 4; i++) {
            const float xi = (i == 0) ? xv.x : (i == 1) ? xv.y : (i == 2) ? xv.z : xv.w;
            const float4* wa = (const float4*)&W1s[i * HID + k0];
            const float4* wb = (const float4*)&W1s[(4 + i) * HID + k0];
            q1a = fma4(xi, wa[0], q1a); q1b = fma4(xi, wa[1], q1b);
            q2a = fma4(xi, wb[0], q2a); q2b = fma4(xi, wb[1], q2b);
        }
        float4* q1w = (float4*)&qp0[n * STR + k0];
        float4* q2w = (float4*)&qp1[n * STR + k0];
        q1w[0] = q1a; q1w[1] = q1b;
        q2w[0] = q2a; q2w[1] = q2b;
    }
    __syncthreads();

    // ---- Stage B: CSR-tiled edge messages via MFMA, owner-gather (no divergent atomics) ----
    {
        const float2* ea2 = (const float2*)edge_attr + (size_t)b * NE;
        const int quad = lane >> 4;
        const int m16  = lane & 15;
        const int kh   = quad * 8;

        const float4* w8p = (const float4*)&W1s[8 * HID + kh];
        const float4* w9p = (const float4*)&W1s[9 * HID + kh];
        const float4 w8a = w8p[0], w8b = w8p[1];
        const float4 w9a = w9p[0], w9b = w9p[1];

        bf16x8 bf0, bf1;   // W2 B-fragments (column halves)
#pragma unroll
        for (int j = 0; j < 8; j++) {
            bf0[j] = f2bf(W2[(kh + j) * HID + m16]);
            bf1[j] = f2bf(W2[(kh + j) * HID + 16 + m16]);
        }

        const int  ntiles = csr[0];
        const int* tile_node = csr + WS_TN;
        const int* pe        = csr + WS_PE;

#pragma unroll 1
        for (int t = wv; t < ntiles; t += TPB / 64) {
            const int node = tile_node[t];              // wave-uniform
            const int e    = pe[t * 16 + m16];          // per-lane edge id, -1 pad
            const int esafe = (e < 0) ? 0 : e;
            const int d0   = ed[esafe];
            const float2 ea = ea2[esafe];

            const float4* Ap = (const float4*)&qp0[node * STR + kh];  // broadcast
            const float4  A0 = Ap[0], A1 = Ap[1];
            const float4* Gp = (const float4*)&qp1[d0 * STR + kh];    // gather
            const float4  G0 = Gp[0], G1 = Gp[1];

            bf16x8 af;
            {
                float h;
                h = A0.x + G0.x + ea.x * w8a.x + ea.y * w9a.x; af[0] = (e < 0) ? (short)0 : f2bf(fmaxf(h, 0.f));
                h = A0.y + G0.y + ea.x * w8a.y + ea.y * w9a.y; af[1] = (e < 0) ? (short)0 : f2bf(fmaxf(h, 0.f));
                h = A0.z + G0.z + ea.x * w8a.z + ea.y * w9a.z; af[2] = (e < 0) ? (short)0 : f2bf(fmaxf(h, 0.f));
                h = A0.w + G0.w + ea.x * w8a.w + ea.y * w9a.w; af[3] = (e < 0) ? (short)0 : f2bf(fmaxf(h, 0.f));
                h = A1.x + G1.x + ea.x * w8b.x + ea.y * w9b.x; af[4] = (e < 0) ? (short)0 : f2bf(fmaxf(h, 0.f));
                h = A1.y + G1.y + ea.x * w8b.y + ea.y * w9b.y; af[5] = (e < 0) ? (short)0 : f2bf(fmaxf(h, 0.f));
                h = A1.z + G1.z + ea.x * w8b.z + ea.y * w9b.z; af[6] = (e < 0) ? (short)0 : f2bf(fmaxf(h, 0.f));
                h = A1.w + G1.w + ea.x * w8b.w + ea.y * w9b.w; af[7] = (e < 0) ? (short)0 : f2bf(fmaxf(h, 0.f));
            }

            f32x4 c0 = {0.f, 0.f, 0.f, 0.f};
            f32x4 c1 = {0.f, 0.f, 0.f, 0.f};
            c0 = __builtin_amdgcn_mfma_f32_16x16x32_bf16(af, bf0, c0, 0, 0, 0);
            c1 = __builtin_amdgcn_mfma_f32_16x16x32_bf16(af, bf1, c1, 0, 0, 0);

            // rows all target `node`: reduce 16 rows -> col totals
            float s0 = c0[0] + c0[1] + c0[2] + c0[3];   // this quad's 4 rows, col m16
            float s1 = c1[0] + c1[1] + c1[2] + c1[3];   // col 16+m16
            s0 += __shfl_xor(s0, 16); s0 += __shfl_xor(s0, 32);
            s1 += __shfl_xor(s1, 16); s1 += __shfl_xor(s1, 32);
            // lane<16: s0 = total col lane; lane in [16,32): s1 = total col lane
            if (lane < 32)
                atomicAdd(&xpp[node * STR + lane], (lane < 16) ? s0 : s1);  // 32 contiguous addrs
        }
    }
    __syncthreads();

    // ---- Stage P: per-node head projections (xpp_eff = xpp + deg*b2) ----
    {
        const float4 xv = xs4[n];
        const float dn = (float)csr[WS_DEG + n];
        const float4* blv = (const float4*)&bls[k0];
        float4 p1a = blv[0], p1b = blv[1];
        float4 p2a = make_float4(0.f, 0.f, 0.f, 0.f), p2b = p2a;
#pragma unroll 1
        for (int i = 0; i < 4; i++) {
            const float xi = (i == 0) ? xv.x : (i == 1) ? xv.y : (i == 2) ? xv.z : xv.w;
            const float4* wa = (const float4*)&Wls[i * HID + k0];
            const float4* wb = (const float4*)&Wls[(36 + i) * HID + k0];
            p1a = fma4(xi, wa[0], p1a); p1b = fma4(xi, wa[1], p1b);
            p2a = fma4(xi, wb[0], p2a); p2b = fma4(xi, wb[1], p2b);
        }
        const float4* xrv  = (const float4*)&xpp[n * STR];
        const float4* b2v4 = (const float4*)b2s;
#pragma unroll 1
        for (int q = 0; q < 8; q++) {
            float4 xq = xrv[q];
            const float4 bq = b2v4[q];
            xq.x = fmaf(dn, bq.x, xq.x); xq.y = fmaf(dn, bq.y, xq.y);
            xq.z = fmaf(dn, bq.z, xq.z); xq.w = fmaf(dn, bq.w, xq.w);
            const int j = q * 4;
#pragma unroll
            for (int u = 0; u < 4; u++) {
                const float xj = (u == 0) ? xq.x : (u == 1) ? xq.y : (u == 2) ? xq.z : xq.w;
                const float4* wa = (const float4*)&Wls[(4 + j + u) * HID + k0];
                const float4* wb = (const float4*)&Wls[(40 + j + u) * HID + k0];
                p1a = fma4(xj, wa[0], p1a); p1b = fma4(xj, wa[1], p1b);
                p2a = fma4(xj, wb[0], p2a); p2b = fma4(xj, wb[1], p2b);
            }
        }
        float4* p1w = (float4*)&qp0[n * STR + k0];
        float4* p2w = (float4*)&qp1[n * STR + k0];
        p1w[0] = p1a; p1w[1] = p1b;
        p2w[0] = p2a; p2w[1] = p2b;
    }
    __syncthreads();

    // ---- Stage C: per-row combine + value head ----
    float vsum = 0.0f;
    {
        const float* actb = action + (size_t)b * NROWS;
        const float bvv = bv[0];
        const float* Wl72 = Wl + 72 * HID;
#pragma unroll 1
        for (int r = tid; r < NROWS; r += TPB) {
            int na, nb;
            if (r < NE) { na = es[r]; nb = ed[r]; }
            else        { na = NNODES - NFACT + (r - NE); nb = na; }
            const float a = actb[r];
            const float4* p1v = (const float4*)&qp0[na * STR];
            const float4* p2v = (const float4*)&qp1[nb * STR];
            float v = bvv;
#pragma unroll 1
            for (int q = 0; q < 8; q += 2) {
                const float4 pa0 = p1v[q],     pb0 = p2v[q];
                const float4 pa1 = p1v[q + 1], pb1 = p2v[q + 1];
                const int k = q * 4;
                v += fmaxf(pa0.x + pb0.x + a * Wl72[k+0], 0.f) * Wv[k+0];
                v += fmaxf(pa0.y + pb0.y + a * Wl72[k+1], 0.f) * Wv[k+1];
                v += fmaxf(pa0.z + pb0.z + a * Wl72[k+2], 0.f) * Wv[k+2];
                v += fmaxf(pa0.w + pb0.w + a * Wl72[k+3], 0.f) * Wv[k+3];
                v += fmaxf(pa1.x + pb1.x + a * Wl72[k+4], 0.f) * Wv[k+4];
                v += fmaxf(pa1.y + pb1.y + a * Wl72[k+5], 0.f) * Wv[k+5];
                v += fmaxf(pa1.z + pb1.z + a * Wl72[k+6], 0.f) * Wv[k+6];
                v += fmaxf(pa1.w + pb1.w + a * Wl72[k+7], 0.f) * Wv[k+7];
            }
            vsum += v;
        }
    }

    // ---- block reduction ----
#pragma unroll
    for (int off = 32; off > 0; off >>= 1)
        vsum += __shfl_down(vsum, off, 64);
    if ((tid & 63) == 0) wred[tid >> 6] = vsum;
    __syncthreads();
    if (tid == 0) {
        float t = 0.0f;
#pragma unroll
        for (int w = 0; w < TPB / 64; w++) t += wred[w];
        out[b] = t;
    }
}

extern "C" void kernel_launch(void* const* d_in, const int* in_sizes, int n_in,
                              void* d_out, int out_size, void* d_ws, size_t ws_size,
                              hipStream_t stream) {
    const float* x         = (const float*)d_in[0];
    const float* edge_attr = (const float*)d_in[2];
    const float* action    = (const float*)d_in[3];
    const int*   es        = (const int*)d_in[4];
    const int*   ed        = (const int*)d_in[5];
    const float* W1        = (const float*)d_in[6];
    const float* b1        = (const float*)d_in[7];
    const float* W2        = (const float*)d_in[8];
    const float* b2        = (const float*)d_in[9];
    const float* Wl        = (const float*)d_in[10];
    const float* bl        = (const float*)d_in[11];
    const float* Wv        = (const float*)d_in[12];
    const float* bv        = (const float*)d_in[13];
    float* out = (float*)d_out;
    int*   ws  = (int*)d_ws;

    build_csr<<<dim3(1), dim3(TPB), 0, stream>>>(es, ws);
    critic_fused<<<dim3(out_size), dim3(TPB), 0, stream>>>(
        x, edge_attr, action, es, ed, W1, b1, W2, b2, Wl, bl, Wv, bv, ws, out);
}

// Round 7
// 149.422 us; speedup vs baseline: 1.8593x; 1.0023x over previous
//
#include <hip/hip_runtime.h>

// Problem constants
#define NNODES 64
#define HID 32
#define NFACT 3
#define NE 1024
#define NROWS (NE + NFACT)   // 1027
#define TPB 256
#define STR 36               // row stride (floats) for xpp/qp
#define NTILES 128           // fixed padded tile count (>= max ceil-sum = 124)

// d_ws int layout: [64..127]=deg[n]  [128..255]=tile_node[t]  [256..]=pep[t*16+i]
//   pep packed: low16 = edge id (0xFFFF = pad), high16 = dst node (0 for pad)
#define WS_DEG  64
#define WS_TN   128
#define WS_PE   256

typedef short bf16x8 __attribute__((ext_vector_type(8)));
typedef float f32x4  __attribute__((ext_vector_type(4)));

// round-to-nearest-even two fp32 -> packed bf16x2 (lo | hi<<16)
__device__ __forceinline__ unsigned pack_bf2(float lo, float hi) {
    unsigned ul = __builtin_bit_cast(unsigned, lo);
    unsigned uh = __builtin_bit_cast(unsigned, hi);
    ul += 0x7fffu + ((ul >> 16) & 1u);
    uh += 0x7fffu + ((uh >> 16) & 1u);
    return (ul >> 16) | (uh & 0xffff0000u);
}
__device__ __forceinline__ short f2bf(float f) {
    unsigned u = __builtin_bit_cast(unsigned, f);
    u += 0x7fffu + ((u >> 16) & 1u);
    return (short)(u >> 16);
}
__device__ __forceinline__ float4 fma4(float a, float4 w, float4 c) {
    c.x = fmaf(a, w.x, c.x); c.y = fmaf(a, w.y, c.y);
    c.z = fmaf(a, w.z, c.z); c.w = fmaf(a, w.w, c.w);
    return c;
}

// ---- Kernel 0: CSR of edges grouped by src, 16-edge tiles, dst packed in ----
__global__ __launch_bounds__(TPB) void build_csr(const int* __restrict__ es,
                                                 const int* __restrict__ ed,
                                                 int* __restrict__ ws) {
    __shared__ int sdeg[NNODES], soff[NNODES], scnt[NNODES];
    const int tid = threadIdx.x;
    if (tid < NNODES) { sdeg[tid] = 0; scnt[tid] = 0; }
    // pad-fill tiles & edge slots
    if (tid < NTILES) ws[WS_TN + tid] = 0;
#pragma unroll 1
    for (int i = tid; i < NTILES * 16; i += TPB) ws[WS_PE + i] = 0xFFFF;
    __syncthreads();
#pragma unroll 1
    for (int e = tid; e < NE; e += TPB) atomicAdd(&sdeg[es[e]], 1);
    __syncthreads();
    if (tid == 0) {
        int run = 0;
#pragma unroll 1
        for (int n = 0; n < NNODES; n++) { soff[n] = run; run += (sdeg[n] + 15) >> 4; }
    }
    __syncthreads();
    if (tid < NNODES) {
        ws[WS_DEG + tid] = sdeg[tid];
        const int base = soff[tid], cnt = (sdeg[tid] + 15) >> 4;
#pragma unroll 1
        for (int j = 0; j < cnt; j++) ws[WS_TN + base + j] = tid;
    }
    __syncthreads();
#pragma unroll 1
    for (int e = tid; e < NE; e += TPB) {
        const int n = es[e];
        const int idx = atomicAdd(&scnt[n], 1);
        ws[WS_PE + soff[n] * 16 + idx] = e | (ed[e] << 16);
    }
}

// ---- Kernel 1: fused per-graph critic (factored, CSR-tiled MFMA edge stage) ----
__global__ __launch_bounds__(TPB, 4) void critic_fused(
    const float* __restrict__ x,
    const float* __restrict__ edge_attr,
    const float* __restrict__ action,
    const int*   __restrict__ es,
    const int*   __restrict__ ed,
    const float* __restrict__ W1,
    const float* __restrict__ b1,
    const float* __restrict__ W2,
    const float* __restrict__ b2,
    const float* __restrict__ Wl,
    const float* __restrict__ bl,
    const float* __restrict__ Wv,
    const float* __restrict__ bv,
    const int*   __restrict__ csr,
    float* __restrict__ out)
{
    const int b    = blockIdx.x;
    const int tid  = threadIdx.x;
    const int lane = tid & 63;
    const int wv   = tid >> 6;

    __shared__ float4 xs4[NNODES];
    __shared__ float  xpp[NNODES * STR];
    __shared__ float  qp0[NNODES * STR];      // Q1 then P1
    __shared__ float  qp1[NNODES * STR];      // Q2 then P2
    __shared__ float  W1s[10 * HID];
    __shared__ float  Wls[73 * HID];
    __shared__ float  b1s[HID], bls[HID], b2s[HID];
    __shared__ float  wred[TPB / 64];

    // ---- Stage A: stage x + weights, zero xpp ----
    if (tid < NNODES) xs4[tid] = ((const float4*)x)[b * NNODES + tid];
    {
        float4*       W1s4 = (float4*)W1s;
        const float4* W1g  = (const float4*)W1;
        if (tid < 80) W1s4[tid] = W1g[tid];
        float4*       Wls4 = (float4*)Wls;
        const float4* Wlg  = (const float4*)Wl;
#pragma unroll 1
        for (int i = tid; i < 73 * HID / 4; i += TPB) Wls4[i] = Wlg[i];
        if (tid < HID) { b1s[tid] = b1[tid]; bls[tid] = bl[tid]; b2s[tid] = b2[tid]; }
    }
#pragma unroll 1
    for (int i = tid; i < NNODES * STR; i += TPB) xpp[i] = 0.0f;
    __syncthreads();

    const int n  = tid & 63;
    const int k0 = (tid >> 6) * 8;

    // ---- Stage Q: per-node first-layer partials ----
    {
        const float4 xv = xs4[n];
        const float4* b1v = (const float4*)&b1s[k0];
        float4 q1a = b1v[0], q1b = b1v[1];
        float4 q2a = make_float4(0.f, 0.f, 0.f, 0.f), q2b = q2a;
#pragma unroll 1
        for (int i = 0; i < 4; i++) {
            const float xi = (i == 0) ? xv.x : (i == 1) ? xv.y : (i == 2) ? xv.z : xv.w;
            const float4* wa = (const float4*)&W1s[i * HID + k0];
            const float4* wb = (const float4*)&W1s[(4 + i) * HID + k0];
            q1a = fma4(xi, wa[0], q1a); q1b = fma4(xi, wa[1], q1b);
            q2a = fma4(xi, wb[0], q2a); q2b = fma4(xi, wb[1], q2b);
        }
        float4* q1w = (float4*)&qp0[n * STR + k0];
        float4* q2w = (float4*)&qp1[n * STR + k0];
        q1w[0] = q1a; q1w[1] = q1b;
        q2w[0] = q2a; q2w[1] = q2b;
    }
    __syncthreads();

    // ---- Stage B: CSR-tiled MFMA edge messages, 2-deep software pipeline ----
    {
        const float2* ea2 = (const float2*)edge_attr + (size_t)b * NE;
        const int quad = lane >> 4;
        const int m16  = lane & 15;
        const int kh   = quad * 8;
        const int NW   = TPB / 64;            // 4 waves
        const int NIT  = NTILES / (TPB / 64); // 32 iterations, uniform

        const float4* w8p = (const float4*)&W1s[8 * HID + kh];
        const float4* w9p = (const float4*)&W1s[9 * HID + kh];
        const float4 w8a = w8p[0], w8b = w8p[1];
        const float4 w9a = w9p[0], w9b = w9p[1];

        bf16x8 bf0, bf1;   // W2 B-fragments (column halves)
#pragma unroll
        for (int j = 0; j < 8; j++) {
            bf0[j] = f2bf(W2[(kh + j) * HID + m16]);
            bf1[j] = f2bf(W2[(kh + j) * HID + 16 + m16]);
        }

        const int* tn  = csr + WS_TN;
        const int* pep = csr + WS_PE;

        // pipeline prologue: raw/node 2 deep, ea 1 deep
        int raw0  = pep[wv * 16 + m16];
        int node0 = tn[wv];
        int raw1  = pep[(wv + NW) * 16 + m16];
        int node1 = tn[wv + NW];
        {
            const int e0 = raw0 & 0xFFFF;
        }
        const int e00 = raw0 & 0xFFFF;
        float2 ea0 = ea2[(e00 == 0xFFFF) ? 0 : e00];

#pragma unroll 1
        for (int i = 0; i < NIT; i++) {
            const int t = wv + i * NW;
            // prefetch raw/node for t+2NW
            int raw2 = 0xFFFF, node2 = 0;
            if (i + 2 < NIT) {
                raw2  = pep[(t + 2 * NW) * 16 + m16];
                node2 = tn[t + 2 * NW];
            }
            // prefetch ea for t+NW
            const int e1 = raw1 & 0xFFFF;
            const float2 ea1 = ea2[(e1 == 0xFFFF) ? 0 : e1];

            // ---- compute tile t ----
            const int  node = node0;
            const bool pad  = (raw0 & 0xFFFF) == 0xFFFF;
            const int  d0   = raw0 >> 16;          // 0 for pads
            const float4* Ap = (const float4*)&qp0[node * STR + kh];  // broadcast
            const float4  A0 = Ap[0], A1 = Ap[1];
            const float4* Gp = (const float4*)&qp1[d0 * STR + kh];    // gather
            const float4  G0 = Gp[0], G1 = Gp[1];

            float h0, h1, h2, h3, h4, h5, h6, h7;
            h0 = fmaxf(A0.x + G0.x + ea0.x * w8a.x + ea0.y * w9a.x, 0.f);
            h1 = fmaxf(A0.y + G0.y + ea0.x * w8a.y + ea0.y * w9a.y, 0.f);
            h2 = fmaxf(A0.z + G0.z + ea0.x * w8a.z + ea0.y * w9a.z, 0.f);
            h3 = fmaxf(A0.w + G0.w + ea0.x * w8a.w + ea0.y * w9a.w, 0.f);
            h4 = fmaxf(A1.x + G1.x + ea0.x * w8b.x + ea0.y * w9b.x, 0.f);
            h5 = fmaxf(A1.y + G1.y + ea0.x * w8b.y + ea0.y * w9b.y, 0.f);
            h6 = fmaxf(A1.z + G1.z + ea0.x * w8b.z + ea0.y * w9b.z, 0.f);
            h7 = fmaxf(A1.w + G1.w + ea0.x * w8b.w + ea0.y * w9b.w, 0.f);

            uint4 packed;
            packed.x = pad ? 0u : pack_bf2(h0, h1);
            packed.y = pad ? 0u : pack_bf2(h2, h3);
            packed.z = pad ? 0u : pack_bf2(h4, h5);
            packed.w = pad ? 0u : pack_bf2(h6, h7);
            const bf16x8 af = __builtin_bit_cast(bf16x8, packed);

            f32x4 c0 = {0.f, 0.f, 0.f, 0.f};
            f32x4 c1 = {0.f, 0.f, 0.f, 0.f};
            c0 = __builtin_amdgcn_mfma_f32_16x16x32_bf16(af, bf0, c0, 0, 0, 0);
            c1 = __builtin_amdgcn_mfma_f32_16x16x32_bf16(af, bf1, c1, 0, 0, 0);

            // all 16 rows target `node`: reduce rows -> column totals
            float s0 = c0[0] + c0[1] + c0[2] + c0[3];
            float s1 = c1[0] + c1[1] + c1[2] + c1[3];
            s0 += __shfl_xor(s0, 16); s0 += __shfl_xor(s0, 32);
            s1 += __shfl_xor(s1, 16); s1 += __shfl_xor(s1, 32);
            if (lane < 32)
                atomicAdd(&xpp[node * STR + lane], (lane < 16) ? s0 : s1);

            // rotate pipeline
            raw0 = raw1; node0 = node1; ea0 = ea1;
            raw1 = raw2; node1 = node2;
        }
    }
    __syncthreads();

    // ---- Stage P: per-node head projections (xpp_eff = xpp + deg*b2) ----
    {
        const float4 xv = xs4[n];
        const float dn = (float)csr[WS_DEG + n];
        const float4* blv = (const float4*)&bls[k0];
        float4 p1a = blv[0], p1b = blv[1];
        float4 p2a = make_float4(0.f, 0.f, 0.f, 0.f), p2b = p2a;
#pragma unroll 1
        for (int i = 0; i < 4; i++) {
            const float xi = (i == 0) ? xv.x : (i == 1) ? xv.y : (i == 2) ? xv.z : xv.w;
            const float4* wa = (const float4*)&Wls[i * HID + k0];
            const float4* wb = (const float4*)&Wls[(36 + i) * HID + k0];
            p1a = fma4(xi, wa[0], p1a); p1b = fma4(xi, wa[1], p1b);
            p2a = fma4(xi, wb[0], p2a); p2b = fma4(xi, wb[1], p2b);
        }
        const float4* xrv  = (const float4*)&xpp[n * STR];
        const float4* b2v4 = (const float4*)b2s;
#pragma unroll 1
        for (int q = 0; q < 8; q++) {
            float4 xq = xrv[q];
            const float4 bq = b2v4[q];
            xq.x = fmaf(dn, bq.x, xq.x); xq.y = fmaf(dn, bq.y, xq.y);
            xq.z = fmaf(dn, bq.z, xq.z); xq.w = fmaf(dn, bq.w, xq.w);
            const int j = q * 4;
#pragma unroll
            for (int u = 0; u < 4; u++) {
                const float xj = (u == 0) ? xq.x : (u == 1) ? xq.y : (u == 2) ? xq.z : xq.w;
                const float4* wa = (const float4*)&Wls[(4 + j + u) * HID + k0];
                const float4* wb = (const float4*)&Wls[(40 + j + u) * HID + k0];
                p1a = fma4(xj, wa[0], p1a); p1b = fma4(xj, wa[1], p1b);
                p2a = fma4(xj, wb[0], p2a); p2b = fma4(xj, wb[1], p2b);
            }
        }
        float4* p1w = (float4*)&qp0[n * STR + k0];
        float4* p2w = (float4*)&qp1[n * STR + k0];
        p1w[0] = p1a; p1w[1] = p1b;
        p2w[0] = p2a; p2w[1] = p2b;
    }
    __syncthreads();

    // ---- Stage C: per-row combine + value head (1-deep prefetch) ----
    float vsum = 0.0f;
    {
        const float* actb = action + (size_t)b * NROWS;
        const float bvv = bv[0];
        const float* Wl72 = Wl + 72 * HID;

        int na0 = es[tid], nb0 = ed[tid];
        float a0 = actb[tid];
#pragma unroll 1
        for (int i = 0; i < 4; i++) {
            int na1 = 0, nb1 = 0; float a1 = 0.f;
            if (i < 3) {
                const int rn = tid + (i + 1) * TPB;
                na1 = es[rn]; nb1 = ed[rn]; a1 = actb[rn];
            }
            const float4* p1v = (const float4*)&qp0[na0 * STR];
            const float4* p2v = (const float4*)&qp1[nb0 * STR];
            float v = bvv;
#pragma unroll 1
            for (int q = 0; q < 8; q += 2) {
                const float4 pa0 = p1v[q],     pb0 = p2v[q];
                const float4 pa1 = p1v[q + 1], pb1 = p2v[q + 1];
                const int k = q * 4;
                v += fmaxf(pa0.x + pb0.x + a0 * Wl72[k+0], 0.f) * Wv[k+0];
                v += fmaxf(pa0.y + pb0.y + a0 * Wl72[k+1], 0.f) * Wv[k+1];
                v += fmaxf(pa0.z + pb0.z + a0 * Wl72[k+2], 0.f) * Wv[k+2];
                v += fmaxf(pa0.w + pb0.w + a0 * Wl72[k+3], 0.f) * Wv[k+3];
                v += fmaxf(pa1.x + pb1.x + a0 * Wl72[k+4], 0.f) * Wv[k+4];
                v += fmaxf(pa1.y + pb1.y + a0 * Wl72[k+5], 0.f) * Wv[k+5];
                v += fmaxf(pa1.z + pb1.z + a0 * Wl72[k+6], 0.f) * Wv[k+6];
                v += fmaxf(pa1.w + pb1.w + a0 * Wl72[k+7], 0.f) * Wv[k+7];
            }
            vsum += v;
            na0 = na1; nb0 = nb1; a0 = a1;
        }
        // factory rows 1024..1026 (na == nb)
        if (tid < NFACT) {
            const int r = NE + tid;
            const int na = NNODES - NFACT + tid;
            const float a = actb[r];
            const float4* p1v = (const float4*)&qp0[na * STR];
            const float4* p2v = (const float4*)&qp1[na * STR];
            float v = bvv;
#pragma unroll 1
            for (int q = 0; q < 8; q += 2) {
                const float4 pa0 = p1v[q],     pb0 = p2v[q];
                const float4 pa1 = p1v[q + 1], pb1 = p2v[q + 1];
                const int k = q * 4;
                v += fmaxf(pa0.x + pb0.x + a * Wl72[k+0], 0.f) * Wv[k+0];
                v += fmaxf(pa0.y + pb0.y + a * Wl72[k+1], 0.f) * Wv[k+1];
                v += fmaxf(pa0.z + pb0.z + a * Wl72[k+2], 0.f) * Wv[k+2];
                v += fmaxf(pa0.w + pb0.w + a * Wl72[k+3], 0.f) * Wv[k+3];
                v += fmaxf(pa1.x + pb1.x + a * Wl72[k+4], 0.f) * Wv[k+4];
                v += fmaxf(pa1.y + pb1.y + a * Wl72[k+5], 0.f) * Wv[k+5];
                v += fmaxf(pa1.z + pb1.z + a * Wl72[k+6], 0.f) * Wv[k+6];
                v += fmaxf(pa1.w + pb1.w + a * Wl72[k+7], 0.f) * Wv[k+7];
            }
            vsum += v;
        }
    }

    // ---- block reduction ----
#pragma unroll
    for (int off = 32; off > 0; off >>= 1)
        vsum += __shfl_down(vsum, off, 64);
    if ((tid & 63) == 0) wred[tid >> 6] = vsum;
    __syncthreads();
    if (tid == 0) {
        float t = 0.0f;
#pragma unroll
        for (int w = 0; w < TPB / 64; w++) t += wred[w];
        out[b] = t;
    }
}

extern "C" void kernel_launch(void* const* d_in, const int* in_sizes, int n_in,
                              void* d_out, int out_size, void* d_ws, size_t ws_size,
                              hipStream_t stream) {
    const float* x         = (const float*)d_in[0];
    const float* edge_attr = (const float*)d_in[2];
    const float* action    = (const float*)d_in[3];
    const int*   es        = (const int*)d_in[4];
    const int*   ed        = (const int*)d_in[5];
    const float* W1        = (const float*)d_in[6];
    const float* b1        = (const float*)d_in[7];
    const float* W2        = (const float*)d_in[8];
    const float* b2        = (const float*)d_in[9];
    const float* Wl        = (const float*)d_in[10];
    const float* bl        = (const float*)d_in[11];
    const float* Wv        = (const float*)d_in[12];
    const float* bv        = (const float*)d_in[13];
    float* out = (float*)d_out;
    int*   ws  = (int*)d_ws;

    build_csr<<<dim3(1), dim3(TPB), 0, stream>>>(es, ed, ws);
    critic_fused<<<dim3(out_size), dim3(TPB), 0, stream>>>(
        x, edge_attr, action, es, ed, W1, b1, W2, b2, Wl, bl, Wv, bv, ws, out);
}

// Round 8
// 142.178 us; speedup vs baseline: 1.9540x; 1.0509x over previous
//
#include <hip/hip_runtime.h>

// Problem constants
#define NNODES 64
#define HID 32
#define NFACT 3
#define NE 1024
#define NROWS (NE + NFACT)   // 1027
#define TPB 256
#define STR 36               // row stride (floats) for xpp/qp
#define MAXTILES 128         // capacity bound (true max = 124)

// d_ws int layout: [0]=ntiles  [64..127]=deg[n]  [128..255]=tile_node[t]  [256..]=pep[t*16+i]
//   pep packed: low16 = edge id (0xFFFF = pad), high16 = dst node (0 for pad)
#define WS_DEG  64
#define WS_TN   128
#define WS_PE   256

typedef short bf16x8 __attribute__((ext_vector_type(8)));
typedef float f32x4  __attribute__((ext_vector_type(4)));

// round-to-nearest-even two fp32 -> packed bf16x2 (lo | hi<<16)
__device__ __forceinline__ unsigned pack_bf2(float lo, float hi) {
    unsigned ul = __builtin_bit_cast(unsigned, lo);
    unsigned uh = __builtin_bit_cast(unsigned, hi);
    ul += 0x7fffu + ((ul >> 16) & 1u);
    uh += 0x7fffu + ((uh >> 16) & 1u);
    return (ul >> 16) | (uh & 0xffff0000u);
}
__device__ __forceinline__ short f2bf(float f) {
    unsigned u = __builtin_bit_cast(unsigned, f);
    u += 0x7fffu + ((u >> 16) & 1u);
    return (short)(u >> 16);
}
__device__ __forceinline__ float4 fma4(float a, float4 w, float4 c) {
    c.x = fmaf(a, w.x, c.x); c.y = fmaf(a, w.y, c.y);
    c.z = fmaf(a, w.z, c.z); c.w = fmaf(a, w.w, c.w);
    return c;
}

// ---- Kernel 0: CSR of edges grouped by src, 16-edge tiles, dst packed in ----
__global__ __launch_bounds__(TPB) void build_csr(const int* __restrict__ es,
                                                 const int* __restrict__ ed,
                                                 int* __restrict__ ws) {
    __shared__ int sdeg[NNODES], soff[NNODES], scnt[NNODES];
    const int tid = threadIdx.x;
    if (tid < NNODES) { sdeg[tid] = 0; scnt[tid] = 0; }
    if (tid < MAXTILES) ws[WS_TN + tid] = 0;
#pragma unroll 1
    for (int i = tid; i < MAXTILES * 16; i += TPB) ws[WS_PE + i] = 0xFFFF;
    __syncthreads();
#pragma unroll 1
    for (int e = tid; e < NE; e += TPB) atomicAdd(&sdeg[es[e]], 1);
    __syncthreads();
    if (tid == 0) {
        int run = 0;
#pragma unroll 1
        for (int n = 0; n < NNODES; n++) { soff[n] = run; run += (sdeg[n] + 15) >> 4; }
        ws[0] = run;   // dynamic tile count (~90-96 typical, <=124)
    }
    __syncthreads();
    if (tid < NNODES) {
        ws[WS_DEG + tid] = sdeg[tid];
        const int base = soff[tid], cnt = (sdeg[tid] + 15) >> 4;
#pragma unroll 1
        for (int j = 0; j < cnt; j++) ws[WS_TN + base + j] = tid;
    }
    __syncthreads();
#pragma unroll 1
    for (int e = tid; e < NE; e += TPB) {
        const int n = es[e];
        const int idx = atomicAdd(&scnt[n], 1);
        ws[WS_PE + soff[n] * 16 + idx] = e | (ed[e] << 16);
    }
}

// ---- Kernel 1: fused per-graph critic (factored, CSR-tiled MFMA edge stage) ----
__global__ __launch_bounds__(TPB, 4) void critic_fused(
    const float* __restrict__ x,
    const float* __restrict__ edge_attr,
    const float* __restrict__ action,
    const int*   __restrict__ es,
    const int*   __restrict__ ed,
    const float* __restrict__ W1,
    const float* __restrict__ b1,
    const float* __restrict__ W2,
    const float* __restrict__ b2,
    const float* __restrict__ Wl,
    const float* __restrict__ bl,
    const float* __restrict__ Wv,
    const float* __restrict__ bv,
    const int*   __restrict__ csr,
    float* __restrict__ out)
{
    const int b    = blockIdx.x;
    const int tid  = threadIdx.x;
    const int lane = tid & 63;
    const int wv   = tid >> 6;

    __shared__ float4 xs4[NNODES];
    __shared__ float  xpp[NNODES * STR];
    __shared__ float  qp0[NNODES * STR];      // Q1 then P1
    __shared__ float  qp1[NNODES * STR];      // Q2 then P2
    __shared__ float  W1s[10 * HID];
    __shared__ float  Wls[73 * HID];
    __shared__ float  b1s[HID], bls[HID], b2s[HID];
    __shared__ float  wred[TPB / 64];

    // ---- Stage A: stage x + weights, zero xpp ----
    if (tid < NNODES) xs4[tid] = ((const float4*)x)[b * NNODES + tid];
    {
        float4*       W1s4 = (float4*)W1s;
        const float4* W1g  = (const float4*)W1;
        if (tid < 80) W1s4[tid] = W1g[tid];
        float4*       Wls4 = (float4*)Wls;
        const float4* Wlg  = (const float4*)Wl;
#pragma unroll 1
        for (int i = tid; i < 73 * HID / 4; i += TPB) Wls4[i] = Wlg[i];
        if (tid < HID) { b1s[tid] = b1[tid]; bls[tid] = bl[tid]; b2s[tid] = b2[tid]; }
    }
#pragma unroll 1
    for (int i = tid; i < NNODES * STR; i += TPB) xpp[i] = 0.0f;
    __syncthreads();

    const int n  = tid & 63;
    const int k0 = (tid >> 6) * 8;

    // ---- Stage Q: per-node first-layer partials ----
    {
        const float4 xv = xs4[n];
        const float4* b1v = (const float4*)&b1s[k0];
        float4 q1a = b1v[0], q1b = b1v[1];
        float4 q2a = make_float4(0.f, 0.f, 0.f, 0.f), q2b = q2a;
#pragma unroll 1
        for (int i = 0; i < 4; i++) {
            const float xi = (i == 0) ? xv.x : (i == 1) ? xv.y : (i == 2) ? xv.z : xv.w;
            const float4* wa = (const float4*)&W1s[i * HID + k0];
            const float4* wb = (const float4*)&W1s[(4 + i) * HID + k0];
            q1a = fma4(xi, wa[0], q1a); q1b = fma4(xi, wa[1], q1b);
            q2a = fma4(xi, wb[0], q2a); q2b = fma4(xi, wb[1], q2b);
        }
        float4* q1w = (float4*)&qp0[n * STR + k0];
        float4* q2w = (float4*)&qp1[n * STR + k0];
        q1w[0] = q1a; q1w[1] = q1b;
        q2w[0] = q2a; q2w[1] = q2b;
    }
    __syncthreads();

    // ---- Stage B: CSR-tiled MFMA edge messages (dynamic tile count) ----
    {
        const float2* ea2 = (const float2*)edge_attr + (size_t)b * NE;
        const int quad = lane >> 4;
        const int m16  = lane & 15;
        const int kh   = quad * 8;
        const int NW   = TPB / 64;

        const float4* w8p = (const float4*)&W1s[8 * HID + kh];
        const float4* w9p = (const float4*)&W1s[9 * HID + kh];
        const float4 w8a = w8p[0], w8b = w8p[1];
        const float4 w9a = w9p[0], w9b = w9p[1];

        bf16x8 bf0, bf1;   // W2 B-fragments (column halves)
#pragma unroll
        for (int j = 0; j < 8; j++) {
            bf0[j] = f2bf(W2[(kh + j) * HID + m16]);
            bf1[j] = f2bf(W2[(kh + j) * HID + 16 + m16]);
        }

        const int  ntiles = csr[0];
        const int* tn  = csr + WS_TN;
        const int* pep = csr + WS_PE;

#pragma unroll 1
        for (int t = wv; t < ntiles; t += NW) {
            const int raw  = pep[t * 16 + m16];
            const int node = tn[t];                    // wave-uniform
            const int e    = raw & 0xFFFF;
            const bool pad = (e == 0xFFFF);
            const int d0   = raw >> 16;                // dst node (0 for pad)
            const float2 ea = ea2[pad ? 0 : e];

            const float4* Ap = (const float4*)&qp0[node * STR + kh];  // broadcast
            const float4  A0 = Ap[0], A1 = Ap[1];
            const float4* Gp = (const float4*)&qp1[d0 * STR + kh];    // gather
            const float4  G0 = Gp[0], G1 = Gp[1];

            const float h0 = fmaxf(A0.x + G0.x + ea.x * w8a.x + ea.y * w9a.x, 0.f);
            const float h1 = fmaxf(A0.y + G0.y + ea.x * w8a.y + ea.y * w9a.y, 0.f);
            const float h2 = fmaxf(A0.z + G0.z + ea.x * w8a.z + ea.y * w9a.z, 0.f);
            const float h3 = fmaxf(A0.w + G0.w + ea.x * w8a.w + ea.y * w9a.w, 0.f);
            const float h4 = fmaxf(A1.x + G1.x + ea.x * w8b.x + ea.y * w9b.x, 0.f);
            const float h5 = fmaxf(A1.y + G1.y + ea.x * w8b.y + ea.y * w9b.y, 0.f);
            const float h6 = fmaxf(A1.z + G1.z + ea.x * w8b.z + ea.y * w9b.z, 0.f);
            const float h7 = fmaxf(A1.w + G1.w + ea.x * w8b.w + ea.y * w9b.w, 0.f);

            uint4 packed;
            packed.x = pad ? 0u : pack_bf2(h0, h1);
            packed.y = pad ? 0u : pack_bf2(h2, h3);
            packed.z = pad ? 0u : pack_bf2(h4, h5);
            packed.w = pad ? 0u : pack_bf2(h6, h7);
            const bf16x8 af = __builtin_bit_cast(bf16x8, packed);

            f32x4 c0 = {0.f, 0.f, 0.f, 0.f};
            f32x4 c1 = {0.f, 0.f, 0.f, 0.f};
            c0 = __builtin_amdgcn_mfma_f32_16x16x32_bf16(af, bf0, c0, 0, 0, 0);
            c1 = __builtin_amdgcn_mfma_f32_16x16x32_bf16(af, bf1, c1, 0, 0, 0);

            // all 16 rows target `node`: reduce rows -> column totals
            float s0 = c0[0] + c0[1] + c0[2] + c0[3];
            float s1 = c1[0] + c1[1] + c1[2] + c1[3];
            s0 += __shfl_xor(s0, 16); s0 += __shfl_xor(s0, 32);
            s1 += __shfl_xor(s1, 16); s1 += __shfl_xor(s1, 32);
            if (lane < 32)
                atomicAdd(&xpp[node * STR + lane], (lane < 16) ? s0 : s1);
        }
    }
    __syncthreads();

    // ---- Stage P: per-node head projections (xpp_eff = xpp + deg*b2) ----
    {
        const float4 xv = xs4[n];
        const float dn = (float)csr[WS_DEG + n];
        const float4* blv = (const float4*)&bls[k0];
        float4 p1a = blv[0], p1b = blv[1];
        float4 p2a = make_float4(0.f, 0.f, 0.f, 0.f), p2b = p2a;
#pragma unroll 1
        for (int i = 0; i < 4; i++) {
            const float xi = (i == 0) ? xv.x : (i == 1) ? xv.y : (i == 2) ? xv.z : xv.w;
            const float4* wa = (const float4*)&Wls[i * HID + k0];
            const float4* wb = (const float4*)&Wls[(36 + i) * HID + k0];
            p1a = fma4(xi, wa[0], p1a); p1b = fma4(xi, wa[1], p1b);
            p2a = fma4(xi, wb[0], p2a); p2b = fma4(xi, wb[1], p2b);
        }
        const float4* xrv  = (const float4*)&xpp[n * STR];
        const float4* b2v4 = (const float4*)b2s;
#pragma unroll 1
        for (int q = 0; q < 8; q++) {
            float4 xq = xrv[q];
            const float4 bq = b2v4[q];
            xq.x = fmaf(dn, bq.x, xq.x); xq.y = fmaf(dn, bq.y, xq.y);
            xq.z = fmaf(dn, bq.z, xq.z); xq.w = fmaf(dn, bq.w, xq.w);
            const int j = q * 4;
#pragma unroll
            for (int u = 0; u < 4; u++) {
                const float xj = (u == 0) ? xq.x : (u == 1) ? xq.y : (u == 2) ? xq.z : xq.w;
                const float4* wa = (const float4*)&Wls[(4 + j + u) * HID + k0];
                const float4* wb = (const float4*)&Wls[(40 + j + u) * HID + k0];
                p1a = fma4(xj, wa[0], p1a); p1b = fma4(xj, wa[1], p1b);
                p2a = fma4(xj, wb[0], p2a); p2b = fma4(xj, wb[1], p2b);
            }
        }
        float4* p1w = (float4*)&qp0[n * STR + k0];
        float4* p2w = (float4*)&qp1[n * STR + k0];
        p1w[0] = p1a; p1w[1] = p1b;
        p2w[0] = p2a; p2w[1] = p2b;
    }
    __syncthreads();

    // ---- Stage C: per-row combine + value head (dual accumulator chains) ----
    float vsum = 0.0f;
    {
        const float* actb = action + (size_t)b * NROWS;
        const float bvv = bv[0];
        const float* Wl72 = Wl + 72 * HID;   // loop-invariant s_loads, hoisted
#pragma unroll 1
        for (int i = 0; i < 4; i++) {
            const int r = tid + i * TPB;
            const int na = es[r], nb = ed[r];
            const float a = actb[r];
            const float4* p1v = (const float4*)&qp0[na * STR];
            const float4* p2v = (const float4*)&qp1[nb * STR];
            float v0 = bvv, v1 = 0.0f;
#pragma unroll 1
            for (int q = 0; q < 8; q += 2) {
                const float4 pa0 = p1v[q],     pb0 = p2v[q];
                const float4 pa1 = p1v[q + 1], pb1 = p2v[q + 1];
                const int k = q * 4;
                v0 += fmaxf(pa0.x + pb0.x + a * Wl72[k+0], 0.f) * Wv[k+0];
                v1 += fmaxf(pa0.y + pb0.y + a * Wl72[k+1], 0.f) * Wv[k+1];
                v0 += fmaxf(pa0.z + pb0.z + a * Wl72[k+2], 0.f) * Wv[k+2];
                v1 += fmaxf(pa0.w + pb0.w + a * Wl72[k+3], 0.f) * Wv[k+3];
                v0 += fmaxf(pa1.x + pb1.x + a * Wl72[k+4], 0.f) * Wv[k+4];
                v1 += fmaxf(pa1.y + pb1.y + a * Wl72[k+5], 0.f) * Wv[k+5];
                v0 += fmaxf(pa1.z + pb1.z + a * Wl72[k+6], 0.f) * Wv[k+6];
                v1 += fmaxf(pa1.w + pb1.w + a * Wl72[k+7], 0.f) * Wv[k+7];
            }
            vsum += v0 + v1;
        }
        // factory rows 1024..1026 (na == nb)
        if (tid < NFACT) {
            const int r = NE + tid;
            const int na = NNODES - NFACT + tid;
            const float a = actb[r];
            const float4* p1v = (const float4*)&qp0[na * STR];
            const float4* p2v = (const float4*)&qp1[na * STR];
            float v = bvv;
#pragma unroll 1
            for (int q = 0; q < 8; q++) {
                const float4 pa = p1v[q], pb = p2v[q];
                const int k = q * 4;
                v += fmaxf(pa.x + pb.x + a * Wl72[k+0], 0.f) * Wv[k+0];
                v += fmaxf(pa.y + pb.y + a * Wl72[k+1], 0.f) * Wv[k+1];
                v += fmaxf(pa.z + pb.z + a * Wl72[k+2], 0.f) * Wv[k+2];
                v += fmaxf(pa.w + pb.w + a * Wl72[k+3], 0.f) * Wv[k+3];
            }
            vsum += v;
        }
    }

    // ---- block reduction ----
#pragma unroll
    for (int off = 32; off > 0; off >>= 1)
        vsum += __shfl_down(vsum, off, 64);
    if ((tid & 63) == 0) wred[tid >> 6] = vsum;
    __syncthreads();
    if (tid == 0) {
        float t = 0.0f;
#pragma unroll
        for (int w = 0; w < TPB / 64; w++) t += wred[w];
        out[b] = t;
    }
}

extern "C" void kernel_launch(void* const* d_in, const int* in_sizes, int n_in,
                              void* d_out, int out_size, void* d_ws, size_t ws_size,
                              hipStream_t stream) {
    const float* x         = (const float*)d_in[0];
    const float* edge_attr = (const float*)d_in[2];
    const float* action    = (const float*)d_in[3];
    const int*   es        = (const int*)d_in[4];
    const int*   ed        = (const int*)d_in[5];
    const float* W1        = (const float*)d_in[6];
    const float* b1        = (const float*)d_in[7];
    const float* W2        = (const float*)d_in[8];
    const float* b2        = (const float*)d_in[9];
    const float* Wl        = (const float*)d_in[10];
    const float* bl        = (const float*)d_in[11];
    const float* Wv        = (const float*)d_in[12];
    const float* bv        = (const float*)d_in[13];
    float* out = (float*)d_out;
    int*   ws  = (int*)d_ws;

    build_csr<<<dim3(1), dim3(TPB), 0, stream>>>(es, ed, ws);
    critic_fused<<<dim3(out_size), dim3(TPB), 0, stream>>>(
        x, edge_attr, action, es, ed, W1, b1, W2, b2, Wl, bl, Wv, bv, ws, out);
}